// Round 2
// baseline (3658.018 us; speedup 1.0000x reference)
//
#include <hip/hip_runtime.h>
#include <hip/hip_bf16.h>

#define N_PTS 400000
#define XN 512
#define YN 512
#define BATCHN 4
#define VOX (XN*YN)            // 262144
#define GRID_NUM (BATCHN*VOX)  // 1048576

static __device__ __forceinline__ float relu_(float x){ return fmaxf(x, 0.0f); }
// valid for v >= 0 with buffer pre-zeroed (non-negative IEEE floats order as ints)
static __device__ __forceinline__ void atomic_max_pos(float* a, float v){
    atomicMax((int*)a, __float_as_int(v));
}
static __device__ __forceinline__ int voxel_id(float px, float py, int b){
    int xg = (int)floorf(px*512.0f);
    int yg = (int)floorf(py*512.0f);
    return b*VOX + yg*XN + xg;
}

// ---------------- zero ws (convA + seg0/seg1-in-convB) each launch
__global__ void kZero(float4* __restrict__ p, int n4){
    int i = blockIdx.x*256 + threadIdx.x;
    const float4 z = make_float4(0.f,0.f,0.f,0.f);
    for (; i < n4; i += gridDim.x*256) p[i] = z;
}

// ---------------- diagnostic: ws too small -> encode ws MiB in output
__global__ void kDiag(float* __restrict__ o, int n, float v){
    int i = blockIdx.x*256 + threadIdx.x;
    for (; i < n; i += gridDim.x*256) o[i] = v;
}

// ---------------- Kernel A: pconv0 -> pconv1 -> concat(dx,dy) -> pconv(v0), scatter seg0
__global__ void kA(const int* __restrict__ bid, const float* __restrict__ pts,
                   const float* __restrict__ w0, const float* __restrict__ b0,
                   const float* __restrict__ s0, const float* __restrict__ t0,
                   const float* __restrict__ w1, const float* __restrict__ b1,
                   const float* __restrict__ s1, const float* __restrict__ t1,
                   const float* __restrict__ wv0, const float* __restrict__ bv0,
                   const float* __restrict__ sv0, const float* __restrict__ tv0,
                   float* __restrict__ obuf, float* __restrict__ seg0)
{
    int i = blockIdx.x*256 + threadIdx.x;
    if (i >= N_PTS) return;
    float p[6];
    #pragma unroll
    for (int r=0;r<6;r++) p[r] = pts[r*N_PTS+i];
    int xg = (int)floorf(p[0]*512.0f);
    int yg = (int)floorf(p[1]*512.0f);
    int gid = bid[i]*VOX + yg*XN + xg;

    float h0[16];
    #pragma unroll
    for (int o=0;o<16;o++){
        float a = b0[o];
        #pragma unroll
        for (int k=0;k<6;k++) a = fmaf(w0[o*6+k], p[k], a);
        h0[o] = relu_(fmaf(a, s0[o], t0[o]));
    }
    float h1[16];
    #pragma unroll
    for (int o=0;o<16;o++){
        float a = b1[o];
        #pragma unroll
        for (int k=0;k<16;k++) a = fmaf(w1[o*16+k], h0[k], a);
        h1[o] = relu_(fmaf(a, s1[o], t1[o]));
    }
    float dx = p[0] - ((float)xg + 0.5f)*(1.0f/512.0f);
    float dy = p[1] - ((float)yg + 0.5f)*(1.0f/512.0f);
    #pragma unroll
    for (int o=0;o<16;o++){
        float a = bv0[o];
        #pragma unroll
        for (int k=0;k<16;k++) a = fmaf(wv0[o*18+k], h1[k], a);
        a = fmaf(wv0[o*18+16], dx, a);
        a = fmaf(wv0[o*18+17], dy, a);
        float v = relu_(fmaf(a, sv0[o], tv0[o]));
        obuf[o*N_PTS+i] = v;
        atomic_max_pos(&seg0[(size_t)gid*16+o], v);
    }
}

// ---------------- Kernel B: concat(o, seg0[gid]) -> pconv(v1), scatter seg1 (in-place obuf)
__global__ void kB(const int* __restrict__ bid, const float* __restrict__ pts,
                   const float* __restrict__ w, const float* __restrict__ bb,
                   const float* __restrict__ ss, const float* __restrict__ tt,
                   float* __restrict__ obuf,
                   const float* __restrict__ segin, float* __restrict__ segout)
{
    int i = blockIdx.x*256 + threadIdx.x;
    if (i >= N_PTS) return;
    int gid = voxel_id(pts[i], pts[N_PTS+i], bid[i]);
    float h[32];
    #pragma unroll
    for (int k=0;k<16;k++) h[k] = obuf[k*N_PTS+i];
    const float4* sp = (const float4*)(segin + (size_t)gid*16);
    #pragma unroll
    for (int q=0;q<4;q++){
        float4 v = sp[q];
        h[16+q*4+0]=v.x; h[16+q*4+1]=v.y; h[16+q*4+2]=v.z; h[16+q*4+3]=v.w;
    }
    float o[16];
    #pragma unroll
    for (int c=0;c<16;c++){
        float a = bb[c];
        #pragma unroll
        for (int k=0;k<32;k++) a = fmaf(w[c*32+k], h[k], a);
        o[c] = relu_(fmaf(a, ss[c], tt[c]));
    }
    #pragma unroll
    for (int c=0;c<16;c++){
        obuf[c*N_PTS+i] = o[c];
        atomic_max_pos(&segout[(size_t)gid*16+c], o[c]);
    }
}

// ---------------- Kernel C: concat(o, seg1[gid]) -> pconv(w2)=point0,
//                  scatter NCHW grid, pre-project through w3[:, :32] into d_out
__global__ void kC(const int* __restrict__ bid, const float* __restrict__ pts,
                   const float* __restrict__ w, const float* __restrict__ bb,
                   const float* __restrict__ ss, const float* __restrict__ tt,
                   const float* __restrict__ w3,
                   float* __restrict__ obuf_and_partial,   // d_out: 16ch obuf in, 20ch partial out
                   const float* __restrict__ segin, float* __restrict__ gridA)
{
    int i = blockIdx.x*256 + threadIdx.x;
    if (i >= N_PTS) return;
    int gid = voxel_id(pts[i], pts[N_PTS+i], bid[i]);
    float h[32];
    #pragma unroll
    for (int k=0;k<16;k++) h[k] = obuf_and_partial[k*N_PTS+i];
    const float4* sp = (const float4*)(segin + (size_t)gid*16);
    #pragma unroll
    for (int q=0;q<4;q++){
        float4 v = sp[q];
        h[16+q*4+0]=v.x; h[16+q*4+1]=v.y; h[16+q*4+2]=v.z; h[16+q*4+3]=v.w;
    }
    int b = gid >> 18;           // VOX = 2^18
    int rem = gid & (VOX-1);
    float p0v[32];
    #pragma unroll
    for (int c=0;c<32;c++){
        float a = bb[c];
        #pragma unroll
        for (int k=0;k<32;k++) a = fmaf(w[c*32+k], h[k], a);
        float v = relu_(fmaf(a, ss[c], tt[c]));
        p0v[c] = v;
        atomic_max_pos(&gridA[(size_t)(b*32+c)*VOX + rem], v);
    }
    // partial[k] = w3[k, 0:32] @ point0 ; column i only -> no cross-thread hazard
    #pragma unroll
    for (int k=0;k<20;k++){
        float a = 0.f;
        #pragma unroll
        for (int c=0;c<32;c++) a = fmaf(w3[k*64+c], p0v[c], a);
        obuf_and_partial[(size_t)k*N_PTS+i] = a;
    }
}

// ---------------- dilated 3x3 conv + BN + ReLU, [4,32,512,512]
template<int P, bool NHWC>
__global__ __launch_bounds__(256) void conv3x3(
    const float* __restrict__ in, float* __restrict__ out,
    const float* __restrict__ W, const float* __restrict__ bb,
    const float* __restrict__ ss, const float* __restrict__ tt)
{
    constexpr int TW = 16, TH = 32;
    constexpr int TIW = TW + 2*P, TIH = TH + 2*P;
    __shared__ float sIn[32][TIH][TIW];
    __shared__ float sW[32][9][32];     // [ic][tap][oc]
    const int tid = threadIdx.x;
    const int x0 = blockIdx.x*TW, y0 = blockIdx.y*TH, bz = blockIdx.z;
    const float* inB = in + (size_t)bz*32*VOX;

    for (int idx = tid; idx < 32*9*32; idx += 256){
        int oc = idx & 31, tap = (idx>>5)%9, ic = idx/288;
        sW[ic][tap][oc] = W[(oc*32+ic)*9 + tap];
    }
    for (int idx = tid; idx < 32*TIH*TIW; idx += 256){
        int c = idx % TIW;
        int r = (idx / TIW) % TIH;
        int ic = idx / (TIW*TIH);
        int gy = y0 - P + r, gx = x0 - P + c;
        float v = 0.f;
        if ((unsigned)gy < 512u && (unsigned)gx < 512u)
            v = inB[((size_t)ic*512 + gy)*512 + gx];
        sIn[ic][r][c] = v;
    }
    __syncthreads();

    const int tx = tid & 15, ty = tid >> 4;
    float acc0[32], acc1[32];
    #pragma unroll
    for (int oc=0;oc<32;oc++){ acc0[oc]=0.f; acc1[oc]=0.f; }

    for (int ic=0; ic<32; ic++){
        #pragma unroll
        for (int tap=0; tap<9; tap++){
            const int ky = tap/3, kx = tap%3;
            float v0 = sIn[ic][ty + ky*P][tx + kx*P];
            float v1 = sIn[ic][ty + 16 + ky*P][tx + kx*P];
            const float4* wp = (const float4*)&sW[ic][tap][0];
            #pragma unroll
            for (int q=0;q<8;q++){
                float4 w4 = wp[q];
                acc0[q*4+0] = fmaf(v0, w4.x, acc0[q*4+0]);
                acc0[q*4+1] = fmaf(v0, w4.y, acc0[q*4+1]);
                acc0[q*4+2] = fmaf(v0, w4.z, acc0[q*4+2]);
                acc0[q*4+3] = fmaf(v0, w4.w, acc0[q*4+3]);
                acc1[q*4+0] = fmaf(v1, w4.x, acc1[q*4+0]);
                acc1[q*4+1] = fmaf(v1, w4.y, acc1[q*4+1]);
                acc1[q*4+2] = fmaf(v1, w4.z, acc1[q*4+2]);
                acc1[q*4+3] = fmaf(v1, w4.w, acc1[q*4+3]);
            }
        }
    }
    #pragma unroll
    for (int oc=0; oc<32; oc++){
        float r0 = relu_(fmaf(acc0[oc] + bb[oc], ss[oc], tt[oc]));
        float r1 = relu_(fmaf(acc1[oc] + bb[oc], ss[oc], tt[oc]));
        int gy0 = y0 + ty, gy1 = y0 + ty + 16, gx = x0 + tx;
        if (NHWC){
            out[(((size_t)bz*512 + gy0)*512 + gx)*32 + oc] = r0;
            out[(((size_t)bz*512 + gy1)*512 + gx)*32 + oc] = r1;
        } else {
            out[((size_t)(bz*32+oc)*512 + gy0)*512 + gx] = r0;
            out[((size_t)(bz*32+oc)*512 + gy1)*512 + gx] = r1;
        }
    }
}

// ---------------- bilinear sample (NHWC grid) + add w3[:,32:]@point1 + b3 into d_out
__global__ void kFinal(const int* __restrict__ bid, const float* __restrict__ pts,
                       const float* __restrict__ gridN,
                       const float* __restrict__ w3, const float* __restrict__ b3,
                       float* __restrict__ outp)
{
    int i = blockIdx.x*256 + threadIdx.x;
    if (i >= N_PTS) return;
    float px = pts[i], py = pts[N_PTS+i];
    int b = bid[i];
    float ix = px*512.0f - 1.0f;
    float iy = py*512.0f - 1.0f + (float)(b*512);
    float x0f = floorf(ix), y0f = floorf(iy);
    float wx = ix - x0f, wy = iy - y0f;
    int x0 = (int)x0f, y0 = (int)y0f;

    float p1[32];
    #pragma unroll
    for (int c=0;c<32;c++) p1[c] = 0.f;
    #pragma unroll
    for (int t=0;t<4;t++){
        int yi = y0 + (t>>1);
        int xi = x0 + (t&1);
        if (yi < 0 || yi >= BATCHN*YN || xi < 0 || xi >= XN) continue;
        float wgt = ((t>>1)? wy : 1.0f-wy) * ((t&1)? wx : 1.0f-wx);
        const float4* tp = (const float4*)(gridN + ((size_t)yi*XN + xi)*32);
        #pragma unroll
        for (int q=0;q<8;q++){
            float4 v = tp[q];
            p1[q*4+0] = fmaf(wgt, v.x, p1[q*4+0]);
            p1[q*4+1] = fmaf(wgt, v.y, p1[q*4+1]);
            p1[q*4+2] = fmaf(wgt, v.z, p1[q*4+2]);
            p1[q*4+3] = fmaf(wgt, v.w, p1[q*4+3]);
        }
    }

    #pragma unroll
    for (int k=0;k<20;k++){
        float a = outp[(size_t)k*N_PTS + i] + b3[k];   // partial from kC
        #pragma unroll
        for (int c=0;c<32;c++) a = fmaf(w3[k*64+32+c], p1[c], a);
        outp[(size_t)k*N_PTS + i] = a;
    }
}

extern "C" void kernel_launch(void* const* d_in, const int* in_sizes, int n_in,
                              void* d_out, int out_size, void* d_ws, size_t ws_size,
                              hipStream_t stream)
{
    const int*   bid = (const int*)  d_in[0];
    const float* pts = (const float*)d_in[1];
    const float* w0  = (const float*)d_in[3];
    const float* b0  = (const float*)d_in[4];
    const float* s0  = (const float*)d_in[5];
    const float* t0  = (const float*)d_in[6];
    const float* w1  = (const float*)d_in[7];
    const float* b1  = (const float*)d_in[8];
    const float* s1  = (const float*)d_in[9];
    const float* t1  = (const float*)d_in[10];
    const float* wv0 = (const float*)d_in[11];
    const float* bv0 = (const float*)d_in[12];
    const float* sv0 = (const float*)d_in[13];
    const float* tv0 = (const float*)d_in[14];
    const float* wv1 = (const float*)d_in[15];
    const float* bv1 = (const float*)d_in[16];
    const float* sv1 = (const float*)d_in[17];
    const float* tv1 = (const float*)d_in[18];
    const float* w2  = (const float*)d_in[19];
    const float* b2  = (const float*)d_in[20];
    const float* s2  = (const float*)d_in[21];
    const float* t2  = (const float*)d_in[22];
    const float* w2d = (const float*)d_in[23];
    const float* b2d = (const float*)d_in[24];
    const float* s2d = (const float*)d_in[25];
    const float* t2d = (const float*)d_in[26];
    const float* w3  = (const float*)d_in[27];
    const float* b3  = (const float*)d_in[28];

    const size_t CONV_BYTES = (size_t)BATCHN*32*VOX*4;   // 134,217,728 (128 MiB)
    const size_t NEED = 2*CONV_BYTES;                    // 268,435,456 (256 MiB)
    if (ws_size < NEED){
        // do not fault: report ws budget via output values (absmax ~ ws MiB)
        kDiag<<<512,256,0,stream>>>((float*)d_out, out_size, (float)(ws_size>>20));
        return;
    }

    char* ws = (char*)d_ws;
    float* convA = (float*)(ws);                         // scatter grid / conv ping
    float* convB = (float*)(ws + CONV_BYTES);            // conv pong
    float* seg0  = convB;                                // 64 MiB, dead before conv1
    float* seg1  = (float*)(ws + CONV_BYTES + (size_t)GRID_NUM*16*4);
    float* obuf  = (float*)d_out;                        // 16ch x N in d_out, then 20ch partial

    // zero convA (scatter target) + seg0/seg1 (all of convB)
    kZero<<<2048,256,0,stream>>>((float4*)ws, (int)(NEED/16));

    const int nb = (N_PTS + 255)/256;
    kA<<<nb,256,0,stream>>>(bid, pts, w0,b0,s0,t0, w1,b1,s1,t1, wv0,bv0,sv0,tv0,
                            obuf, seg0);
    kB<<<nb,256,0,stream>>>(bid, pts, wv1,bv1,sv1,tv1, obuf, seg0, seg1);
    kC<<<nb,256,0,stream>>>(bid, pts, w2,b2,s2,t2, w3, obuf, seg1, convA);

    dim3 cgrid(XN/16, YN/32, BATCHN);
    conv3x3<1,false><<<cgrid,256,0,stream>>>(convA, convB, w2d + 0*9216, b2d + 0,  s2d + 0,  t2d + 0);
    conv3x3<2,false><<<cgrid,256,0,stream>>>(convB, convA, w2d + 1*9216, b2d + 32, s2d + 32, t2d + 32);
    conv3x3<2,false><<<cgrid,256,0,stream>>>(convA, convB, w2d + 2*9216, b2d + 64, s2d + 64, t2d + 64);
    conv3x3<2,true ><<<cgrid,256,0,stream>>>(convB, convA, w2d + 3*9216, b2d + 96, s2d + 96, t2d + 96);

    kFinal<<<nb,256,0,stream>>>(bid, pts, convA, w3, b3, (float*)d_out);
}

// Round 3
// 2316.246 us; speedup vs baseline: 1.5793x; 1.5793x over previous
//
#include <hip/hip_runtime.h>
#include <hip/hip_bf16.h>

#define N_PTS 400000
#define XN 512
#define YN 512
#define BATCHN 4
#define VOX (XN*YN)            // 262144
#define GRID_NUM (BATCHN*VOX)  // 1048576

static __device__ __forceinline__ float relu_(float x){ return fmaxf(x, 0.0f); }
// valid for v >= 0 with buffer pre-zeroed (non-negative IEEE floats order as ints)
static __device__ __forceinline__ void atomic_max_pos(float* a, float v){
    atomicMax((int*)a, __float_as_int(v));
}
static __device__ __forceinline__ int voxel_id(float px, float py, int b){
    int xg = (int)floorf(px*512.0f);
    int yg = (int)floorf(py*512.0f);
    return b*VOX + yg*XN + xg;
}

// ---------------- zero ws (convA + seg0/seg1-in-convB) each launch
__global__ void kZero(float4* __restrict__ p, int n4){
    int i = blockIdx.x*256 + threadIdx.x;
    const float4 z = make_float4(0.f,0.f,0.f,0.f);
    for (; i < n4; i += gridDim.x*256) p[i] = z;
}

// ---------------- diagnostic: ws too small -> encode ws MiB in output
__global__ void kDiag(float* __restrict__ o, int n, float v){
    int i = blockIdx.x*256 + threadIdx.x;
    for (; i < n; i += gridDim.x*256) o[i] = v;
}

// ---------------- Kernel A: pconv0 -> pconv1 -> concat(dx,dy) -> pconv(v0), scatter seg0
__global__ void kA(const int* __restrict__ bid, const float* __restrict__ pts,
                   const float* __restrict__ w0, const float* __restrict__ b0,
                   const float* __restrict__ s0, const float* __restrict__ t0,
                   const float* __restrict__ w1, const float* __restrict__ b1,
                   const float* __restrict__ s1, const float* __restrict__ t1,
                   const float* __restrict__ wv0, const float* __restrict__ bv0,
                   const float* __restrict__ sv0, const float* __restrict__ tv0,
                   float* __restrict__ obuf, float* __restrict__ seg0)
{
    int i = blockIdx.x*256 + threadIdx.x;
    if (i >= N_PTS) return;
    float p[6];
    #pragma unroll
    for (int r=0;r<6;r++) p[r] = pts[r*N_PTS+i];
    int xg = (int)floorf(p[0]*512.0f);
    int yg = (int)floorf(p[1]*512.0f);
    int gid = bid[i]*VOX + yg*XN + xg;

    float h0[16];
    #pragma unroll
    for (int o=0;o<16;o++){
        float a = b0[o];
        #pragma unroll
        for (int k=0;k<6;k++) a = fmaf(w0[o*6+k], p[k], a);
        h0[o] = relu_(fmaf(a, s0[o], t0[o]));
    }
    float h1[16];
    #pragma unroll
    for (int o=0;o<16;o++){
        float a = b1[o];
        #pragma unroll
        for (int k=0;k<16;k++) a = fmaf(w1[o*16+k], h0[k], a);
        h1[o] = relu_(fmaf(a, s1[o], t1[o]));
    }
    float dx = p[0] - ((float)xg + 0.5f)*(1.0f/512.0f);
    float dy = p[1] - ((float)yg + 0.5f)*(1.0f/512.0f);
    #pragma unroll
    for (int o=0;o<16;o++){
        float a = bv0[o];
        #pragma unroll
        for (int k=0;k<16;k++) a = fmaf(wv0[o*18+k], h1[k], a);
        a = fmaf(wv0[o*18+16], dx, a);
        a = fmaf(wv0[o*18+17], dy, a);
        float v = relu_(fmaf(a, sv0[o], tv0[o]));
        obuf[o*N_PTS+i] = v;
        atomic_max_pos(&seg0[(size_t)gid*16+o], v);
    }
}

// ---------------- Kernel B: concat(o, seg0[gid]) -> pconv(v1), scatter seg1 (in-place obuf)
__global__ void kB(const int* __restrict__ bid, const float* __restrict__ pts,
                   const float* __restrict__ w, const float* __restrict__ bb,
                   const float* __restrict__ ss, const float* __restrict__ tt,
                   float* __restrict__ obuf,
                   const float* __restrict__ segin, float* __restrict__ segout)
{
    int i = blockIdx.x*256 + threadIdx.x;
    if (i >= N_PTS) return;
    int gid = voxel_id(pts[i], pts[N_PTS+i], bid[i]);
    float h[32];
    #pragma unroll
    for (int k=0;k<16;k++) h[k] = obuf[k*N_PTS+i];
    const float4* sp = (const float4*)(segin + (size_t)gid*16);
    #pragma unroll
    for (int q=0;q<4;q++){
        float4 v = sp[q];
        h[16+q*4+0]=v.x; h[16+q*4+1]=v.y; h[16+q*4+2]=v.z; h[16+q*4+3]=v.w;
    }
    float o[16];
    #pragma unroll
    for (int c=0;c<16;c++){
        float a = bb[c];
        #pragma unroll
        for (int k=0;k<32;k++) a = fmaf(w[c*32+k], h[k], a);
        o[c] = relu_(fmaf(a, ss[c], tt[c]));
    }
    #pragma unroll
    for (int c=0;c<16;c++){
        obuf[c*N_PTS+i] = o[c];
        atomic_max_pos(&segout[(size_t)gid*16+c], o[c]);
    }
}

// ---------------- Kernel C: concat(o, seg1[gid]) -> pconv(w2)=point0,
//                  scatter NCHW grid, pre-project through w3[:, :32] into d_out
__global__ void kC(const int* __restrict__ bid, const float* __restrict__ pts,
                   const float* __restrict__ w, const float* __restrict__ bb,
                   const float* __restrict__ ss, const float* __restrict__ tt,
                   const float* __restrict__ w3,
                   float* __restrict__ obuf_and_partial,   // d_out: 16ch obuf in, 20ch partial out
                   const float* __restrict__ segin, float* __restrict__ gridA)
{
    int i = blockIdx.x*256 + threadIdx.x;
    if (i >= N_PTS) return;
    int gid = voxel_id(pts[i], pts[N_PTS+i], bid[i]);
    float h[32];
    #pragma unroll
    for (int k=0;k<16;k++) h[k] = obuf_and_partial[k*N_PTS+i];
    const float4* sp = (const float4*)(segin + (size_t)gid*16);
    #pragma unroll
    for (int q=0;q<4;q++){
        float4 v = sp[q];
        h[16+q*4+0]=v.x; h[16+q*4+1]=v.y; h[16+q*4+2]=v.z; h[16+q*4+3]=v.w;
    }
    int b = gid >> 18;           // VOX = 2^18
    int rem = gid & (VOX-1);
    float p0v[32];
    #pragma unroll
    for (int c=0;c<32;c++){
        float a = bb[c];
        #pragma unroll
        for (int k=0;k<32;k++) a = fmaf(w[c*32+k], h[k], a);
        float v = relu_(fmaf(a, ss[c], tt[c]));
        p0v[c] = v;
        atomic_max_pos(&gridA[(size_t)(b*32+c)*VOX + rem], v);
    }
    // partial[k] = w3[k, 0:32] @ point0 ; column i only -> no cross-thread hazard
    #pragma unroll
    for (int k=0;k<20;k++){
        float a = 0.f;
        #pragma unroll
        for (int c=0;c<32;c++) a = fmaf(w3[k*64+c], p0v[c], a);
        obuf_and_partial[(size_t)k*N_PTS+i] = a;
    }
}

// ---------------- dilated 3x3 conv + BN + ReLU, [4,32,512,512]
// ic-chunked (8 at a time) -> LDS 32.3 KB -> 3 blocks/CU (12 waves) vs old 1 block.
template<int P, bool NHWC>
__global__ __launch_bounds__(256,3) void conv3x3(
    const float* __restrict__ in, float* __restrict__ out,
    const float* __restrict__ W, const float* __restrict__ bb,
    const float* __restrict__ ss, const float* __restrict__ tt)
{
    constexpr int TW = 32, TH = 16;
    constexpr int TIW = TW + 2*P, TIH = TH + 2*P;   // P=2: 36x20; P=1: 34x18
    constexpr int ICC = 8;                          // ic chunk
    __shared__ float sIn[ICC][TIH][TIW];            // 23 KB (P=2)
    __shared__ float sW[ICC][9][32];                // 9.2 KB
    const int tid = threadIdx.x;
    const int x0 = blockIdx.x*TW, y0 = blockIdx.y*TH, bz = blockIdx.z;
    const float* inB = in + (size_t)bz*32*VOX;
    const int tx = tid & 31, ty = tid >> 5;         // pixel (tx, ty) and (tx, ty+8)

    float acc0[32], acc1[32];
    #pragma unroll
    for (int oc=0;oc<32;oc++){ acc0[oc]=0.f; acc1[oc]=0.f; }

    for (int c0 = 0; c0 < 32; c0 += ICC){
        if (c0) __syncthreads();                    // protect previous chunk's reads
        for (int idx = tid; idx < ICC*9*32; idx += 256){
            int oc = idx & 31, tap = (idx>>5)%9, ic = idx/288;
            sW[ic][tap][oc] = W[((size_t)oc*32 + c0 + ic)*9 + tap];
        }
        for (int idx = tid; idx < ICC*TIH*TIW; idx += 256){
            int c = idx % TIW;
            int r = (idx / TIW) % TIH;
            int ic = idx / (TIW*TIH);
            int gy = y0 - P + r, gx = x0 - P + c;
            float v = 0.f;
            if ((unsigned)gy < 512u && (unsigned)gx < 512u)
                v = inB[((size_t)(c0+ic)*512 + gy)*512 + gx];
            sIn[ic][r][c] = v;
        }
        __syncthreads();

        for (int ic=0; ic<ICC; ic++){
            #pragma unroll
            for (int tap=0; tap<9; tap++){
                const int ky = tap/3, kx = tap%3;
                float v0 = sIn[ic][ty +     ky*P][tx + kx*P];
                float v1 = sIn[ic][ty + 8 + ky*P][tx + kx*P];
                const float4* wp = (const float4*)&sW[ic][tap][0];
                #pragma unroll
                for (int q=0;q<8;q++){
                    float4 w4 = wp[q];
                    acc0[q*4+0] = fmaf(v0, w4.x, acc0[q*4+0]);
                    acc0[q*4+1] = fmaf(v0, w4.y, acc0[q*4+1]);
                    acc0[q*4+2] = fmaf(v0, w4.z, acc0[q*4+2]);
                    acc0[q*4+3] = fmaf(v0, w4.w, acc0[q*4+3]);
                    acc1[q*4+0] = fmaf(v1, w4.x, acc1[q*4+0]);
                    acc1[q*4+1] = fmaf(v1, w4.y, acc1[q*4+1]);
                    acc1[q*4+2] = fmaf(v1, w4.z, acc1[q*4+2]);
                    acc1[q*4+3] = fmaf(v1, w4.w, acc1[q*4+3]);
                }
            }
        }
    }

    #pragma unroll
    for (int oc=0; oc<32; oc++){
        float r0 = relu_(fmaf(acc0[oc] + bb[oc], ss[oc], tt[oc]));
        float r1 = relu_(fmaf(acc1[oc] + bb[oc], ss[oc], tt[oc]));
        int gy0 = y0 + ty, gy1 = y0 + ty + 8, gx = x0 + tx;
        if (NHWC){
            out[(((size_t)bz*512 + gy0)*512 + gx)*32 + oc] = r0;
            out[(((size_t)bz*512 + gy1)*512 + gx)*32 + oc] = r1;
        } else {
            out[((size_t)(bz*32+oc)*512 + gy0)*512 + gx] = r0;
            out[((size_t)(bz*32+oc)*512 + gy1)*512 + gx] = r1;
        }
    }
}

// ---------------- bilinear sample (NHWC grid) + add w3[:,32:]@point1 + b3 into d_out
__global__ void kFinal(const int* __restrict__ bid, const float* __restrict__ pts,
                       const float* __restrict__ gridN,
                       const float* __restrict__ w3, const float* __restrict__ b3,
                       float* __restrict__ outp)
{
    int i = blockIdx.x*256 + threadIdx.x;
    if (i >= N_PTS) return;
    float px = pts[i], py = pts[N_PTS+i];
    int b = bid[i];
    float ix = px*512.0f - 1.0f;
    float iy = py*512.0f - 1.0f + (float)(b*512);
    float x0f = floorf(ix), y0f = floorf(iy);
    float wx = ix - x0f, wy = iy - y0f;
    int x0 = (int)x0f, y0 = (int)y0f;

    float p1[32];
    #pragma unroll
    for (int c=0;c<32;c++) p1[c] = 0.f;
    #pragma unroll
    for (int t=0;t<4;t++){
        int yi = y0 + (t>>1);
        int xi = x0 + (t&1);
        if (yi < 0 || yi >= BATCHN*YN || xi < 0 || xi >= XN) continue;
        float wgt = ((t>>1)? wy : 1.0f-wy) * ((t&1)? wx : 1.0f-wx);
        const float4* tp = (const float4*)(gridN + ((size_t)yi*XN + xi)*32);
        #pragma unroll
        for (int q=0;q<8;q++){
            float4 v = tp[q];
            p1[q*4+0] = fmaf(wgt, v.x, p1[q*4+0]);
            p1[q*4+1] = fmaf(wgt, v.y, p1[q*4+1]);
            p1[q*4+2] = fmaf(wgt, v.z, p1[q*4+2]);
            p1[q*4+3] = fmaf(wgt, v.w, p1[q*4+3]);
        }
    }

    #pragma unroll
    for (int k=0;k<20;k++){
        float a = outp[(size_t)k*N_PTS + i] + b3[k];   // partial from kC
        #pragma unroll
        for (int c=0;c<32;c++) a = fmaf(w3[k*64+32+c], p1[c], a);
        outp[(size_t)k*N_PTS + i] = a;
    }
}

extern "C" void kernel_launch(void* const* d_in, const int* in_sizes, int n_in,
                              void* d_out, int out_size, void* d_ws, size_t ws_size,
                              hipStream_t stream)
{
    const int*   bid = (const int*)  d_in[0];
    const float* pts = (const float*)d_in[1];
    const float* w0  = (const float*)d_in[3];
    const float* b0  = (const float*)d_in[4];
    const float* s0  = (const float*)d_in[5];
    const float* t0  = (const float*)d_in[6];
    const float* w1  = (const float*)d_in[7];
    const float* b1  = (const float*)d_in[8];
    const float* s1  = (const float*)d_in[9];
    const float* t1  = (const float*)d_in[10];
    const float* wv0 = (const float*)d_in[11];
    const float* bv0 = (const float*)d_in[12];
    const float* sv0 = (const float*)d_in[13];
    const float* tv0 = (const float*)d_in[14];
    const float* wv1 = (const float*)d_in[15];
    const float* bv1 = (const float*)d_in[16];
    const float* sv1 = (const float*)d_in[17];
    const float* tv1 = (const float*)d_in[18];
    const float* w2  = (const float*)d_in[19];
    const float* b2  = (const float*)d_in[20];
    const float* s2  = (const float*)d_in[21];
    const float* t2  = (const float*)d_in[22];
    const float* w2d = (const float*)d_in[23];
    const float* b2d = (const float*)d_in[24];
    const float* s2d = (const float*)d_in[25];
    const float* t2d = (const float*)d_in[26];
    const float* w3  = (const float*)d_in[27];
    const float* b3  = (const float*)d_in[28];

    const size_t CONV_BYTES = (size_t)BATCHN*32*VOX*4;   // 134,217,728 (128 MiB)
    const size_t NEED = 2*CONV_BYTES;                    // 268,435,456 (256 MiB)
    if (ws_size < NEED){
        // do not fault: report ws budget via output values (absmax ~ ws MiB)
        kDiag<<<512,256,0,stream>>>((float*)d_out, out_size, (float)(ws_size>>20));
        return;
    }

    char* ws = (char*)d_ws;
    float* convA = (float*)(ws);                         // scatter grid / conv ping
    float* convB = (float*)(ws + CONV_BYTES);            // conv pong
    float* seg0  = convB;                                // 64 MiB, dead before conv1
    float* seg1  = (float*)(ws + CONV_BYTES + (size_t)GRID_NUM*16*4);
    float* obuf  = (float*)d_out;                        // 16ch x N in d_out, then 20ch partial

    // zero convA (scatter target) + seg0/seg1 (all of convB)
    kZero<<<2048,256,0,stream>>>((float4*)ws, (int)(NEED/16));

    const int nb = (N_PTS + 255)/256;
    kA<<<nb,256,0,stream>>>(bid, pts, w0,b0,s0,t0, w1,b1,s1,t1, wv0,bv0,sv0,tv0,
                            obuf, seg0);
    kB<<<nb,256,0,stream>>>(bid, pts, wv1,bv1,sv1,tv1, obuf, seg0, seg1);
    kC<<<nb,256,0,stream>>>(bid, pts, w2,b2,s2,t2, w3, obuf, seg1, convA);

    dim3 cgrid(XN/32, YN/16, BATCHN);
    conv3x3<1,false><<<cgrid,256,0,stream>>>(convA, convB, w2d + 0*9216, b2d + 0,  s2d + 0,  t2d + 0);
    conv3x3<2,false><<<cgrid,256,0,stream>>>(convB, convA, w2d + 1*9216, b2d + 32, s2d + 32, t2d + 32);
    conv3x3<2,false><<<cgrid,256,0,stream>>>(convA, convB, w2d + 2*9216, b2d + 64, s2d + 64, t2d + 64);
    conv3x3<2,true ><<<cgrid,256,0,stream>>>(convB, convA, w2d + 3*9216, b2d + 96, s2d + 96, t2d + 96);

    kFinal<<<nb,256,0,stream>>>(bid, pts, convA, w3, b3, (float*)d_out);
}